// Round 8
// baseline (471.955 us; speedup 1.0000x reference)
//
#include <hip/hip_runtime.h>

// Sudoku GNN: 5x GCNConv (shared graph) + 2-layer MLP head.
// CSR via two-level bucket sort (no global atomics). Weight-free CSR
// (dinv factored into producers/consumers). Pull-based aggs fused with
// the following dense stage through LDS row staging.
// C=32 aggs use EPI=8 + LDS-staged epilogue weights (R5/R7-measured best;
// EPI=16 at C=32 makes the compiler serialize gathers - R6 regression).

#define NN    165888            // total nodes = 2048*81
#define NBAT  2048
#define EPER  1620
#define NEDGE (NBAT * EPER)     // 3,317,760
#define ETOT  (NEDGE + NN)      // 3,483,648 (with self loops)
#define NBKT  648               // buckets of 256 nodes (dst>>8)
#define NBLK  512               // edge-pass blocks, 4 batches each
#define SLICE 20736             // NN/8 (XCD swizzle for node-parallel kernels)
#define BCAP  6144              // LDS pairs cache per bucket (mean 5120, 14 sigma)

// ---------------- block-wide exclusive scan (256 threads) ----------------

__device__ inline void blk_scan256(int val, int& excl, int& total, int* sw) {
  int lane = threadIdx.x & 63, w = threadIdx.x >> 6;
  int x = val;
#pragma unroll
  for (int off = 1; off < 64; off <<= 1) {
    int y = __shfl_up(x, off);
    if (lane >= off) x += y;
  }
  if (lane == 63) sw[w] = x;
  __syncthreads();
  int woff = 0;
  if (w > 0) woff = sw[0];
  if (w > 1) woff += sw[1];
  if (w > 2) woff += sw[2];
  total = sw[0] + sw[1] + sw[2] + sw[3];
  excl = woff + x - val;
}

// Exclusive prefix of btot[648] into LDS pb[648] (3 elements/thread, 648=3*216).
__device__ inline void pbase_scan(const int* __restrict__ btot, int* pb, int* sw) {
  int t = threadIdx.x;
  int e0 = 0, e1 = 0, e2 = 0, s = 0;
  if (t < 216) {
    e0 = btot[3 * t]; e1 = btot[3 * t + 1]; e2 = btot[3 * t + 2];
    s = e0 + e1 + e2;
  }
  int excl, tot;
  blk_scan256(s, excl, tot, sw);
  if (t < 216) {
    pb[3 * t]     = excl;
    pb[3 * t + 1] = excl + e0;
    pb[3 * t + 2] = excl + e0 + e1;
  }
  __syncthreads();
}

// ---------------- preprocessing ----------------

__global__ __launch_bounds__(256) void k_count(const int* __restrict__ ei,
                                               int* __restrict__ counts) {
  __shared__ int cnt[NBKT];
  int t = threadIdx.x;
  for (int k = t; k < NBKT; k += 256) cnt[k] = 0;
  __syncthreads();
  int b0 = blockIdx.x * 4;
  for (int b = b0; b < b0 + 4; ++b) {
    const int* dstp = ei + (size_t)b * (2 * EPER) + EPER;
    for (int e = t; e < EPER; e += 256) atomicAdd(&cnt[dstp[e] >> 8], 1);
  }
  __syncthreads();
  for (int k = t; k < NBKT; k += 256) counts[blockIdx.x * NBKT + k] = cnt[k];
}

__global__ __launch_bounds__(256) void k_scan(const int* __restrict__ counts,
                                              int* __restrict__ basesT,
                                              int* __restrict__ btot) {
  int bkt = blockIdx.x, t = threadIdx.x;
  int a = counts[(2 * t)     * NBKT + bkt];
  int b = counts[(2 * t + 1) * NBKT + bkt];
  __shared__ int sw[4];
  int excl, tot;
  blk_scan256(a + b, excl, tot, sw);
  basesT[bkt * NBLK + 2 * t]     = excl;
  basesT[bkt * NBLK + 2 * t + 1] = excl + a;
  if (t == 255) btot[bkt] = tot;
}

__global__ __launch_bounds__(256) void k_scat(const int* __restrict__ ei,
                                              const int* __restrict__ basesT,
                                              const int* __restrict__ btot,
                                              unsigned int* __restrict__ pairs) {
  __shared__ int cur[NBKT];
  __shared__ int pb[NBKT];
  __shared__ int sw[4];
  pbase_scan(btot, pb, sw);
  int t = threadIdx.x;
  for (int k = t; k < NBKT; k += 256)
    cur[k] = pb[k] + basesT[k * NBLK + blockIdx.x];
  __syncthreads();
  int b0 = blockIdx.x * 4;
  for (int b = b0; b < b0 + 4; ++b) {
    const int* srcp = ei + (size_t)b * (2 * EPER);
    const int* dstp = srcp + EPER;
    for (int e = t; e < EPER; e += 256) {
      int d = dstp[e];
      unsigned int s = (unsigned int)srcp[e];
      int pos = atomicAdd(&cur[d >> 8], 1);
      pairs[pos] = s | ((unsigned int)(d & 255) << 24);
    }
  }
}

// k_build (+fused K1 gemm): CSR rows for one bucket (pairs cached in LDS,
// single global read), dinv, self loops, then g0 = dinv ⊙ (x @ W1).
__global__ __launch_bounds__(256) void k_build(const unsigned int* __restrict__ pairs,
                                               const int* __restrict__ btot,
                                               const float* __restrict__ x,
                                               const float* __restrict__ W1,
                                               int* __restrict__ row_start,
                                               int* __restrict__ row_end,
                                               float* __restrict__ dinv,
                                               int* __restrict__ csr,
                                               float* __restrict__ g0) {
  __shared__ int pb[NBKT];
  __shared__ int sw[4];
  __shared__ int cnt[256];
  __shared__ unsigned int sp[BCAP];
  __shared__ float sW[160];
  int bkt = blockIdx.x, t = threadIdx.x;
  cnt[t] = 0;
  if (t < 160) sW[t] = W1[t];
  pbase_scan(btot, pb, sw);                     // trailing sync orders cnt/sW too
  int p0 = pb[bkt];
  int n  = btot[bkt];
  // single global pass: cache in LDS + histogram
  for (int k = t; k < n; k += 256) {
    unsigned int pr = pairs[p0 + k];
    if (k < BCAP) sp[k] = pr;
    atomicAdd(&cnt[pr >> 24], 1);
  }
  __syncthreads();
  int indeg = cnt[t];
  int excl, tot;
  blk_scan256(indeg, excl, tot, sw);
  int csrbase = p0 + bkt * 256;                 // + self-loop slots of prior buckets
  int rs   = csrbase + excl + t;
  int node = bkt * 256 + t;
  int d    = indeg + 1;
  float di = rsqrtf((float)d);
  row_start[node] = rs;
  row_end[node]   = rs + d;
  dinv[node] = di;
  csr[rs] = node;                               // self loop
  __syncthreads();
  cnt[t] = rs + 1;                              // reuse as cursors
  __syncthreads();
  for (int k = t; k < n; k += 256) {
    unsigned int pr = (k < BCAP) ? sp[k] : pairs[p0 + k];
    int pos = atomicAdd(&cnt[pr >> 24], 1);
    csr[pos] = (int)(pr & 0x00FFFFFFu);
  }
  // fused K1: g0 = dinv ⊙ (x @ W1)  (10 -> 16)
  float r[10];
#pragma unroll
  for (int k = 0; k < 10; ++k) r[k] = x[(size_t)node * 10 + k];
  float acc[16];
#pragma unroll
  for (int j = 0; j < 16; ++j) acc[j] = 0.0f;
#pragma unroll
  for (int k = 0; k < 10; ++k) {
    float rv = r[k];
#pragma unroll
    for (int j = 0; j < 16; ++j) acc[j] = fmaf(rv, sW[k * 16 + j], acc[j]);
  }
  float* op = g0 + (size_t)node * 16;
#pragma unroll
  for (int j = 0; j < 16; j += 4)
    *(float4*)(op + j) = make_float4(acc[j] * di, acc[j+1] * di,
                                     acc[j+2] * di, acc[j+3] * di);
}

// ------------- branchless agg core: EPI gathers in flight -------------
// Clamped slots all read row re-1; sum unweighted, subtract dups*v_last.

template <int C, int EPI>
__device__ inline float4 agg_core(const float* __restrict__ g,
                                  const int* __restrict__ csr,
                                  int rs, int re, int q, int gl) {
  constexpr int LG = C / 4;
  float4 acc = make_float4(0.f, 0.f, 0.f, 0.f);
  const float* gq = g + (size_t)q * 4;
  int iters = 0;
  for (int p = rs; p < re; p += EPI) {
    ++iters;
    int m[EPI / LG];
#pragma unroll
    for (int u = 0; u < EPI / LG; ++u) {
      int idx = p + u * LG + q;
      m[u] = csr[idx < re ? idx : re - 1];
    }
    float4 v[EPI];
#pragma unroll
    for (int j = 0; j < EPI; ++j) {
      int s = __shfl(m[j / LG], gl + (j % LG));
      v[j] = *(const float4*)(gq + (size_t)s * C);
    }
#pragma unroll
    for (int j = 0; j < EPI; ++j) {
      acc.x += v[j].x; acc.y += v[j].y; acc.z += v[j].z; acc.w += v[j].w;
    }
  }
  float dups = (float)(iters * EPI - (re - rs));
  int slast = csr[re - 1];
  float4 vl = *(const float4*)(gq + (size_t)slast * C);
  acc.x = fmaf(-dups, vl.x, acc.x);
  acc.y = fmaf(-dups, vl.y, acc.y);
  acc.z = fmaf(-dups, vl.z, acc.z);
  acc.w = fmaf(-dups, vl.w, acc.w);
  return acc;
}

// ---------------- K2: g1 = dinv ⊙ relu(dinv·Σg0 + b1)  (C=16) ----------------

__global__ __launch_bounds__(256) void k_agg_ep16(const float* __restrict__ g,
                                                  const int* __restrict__ row_start,
                                                  const int* __restrict__ row_end,
                                                  const int* __restrict__ csr,
                                                  const float* __restrict__ dinv,
                                                  const float* __restrict__ bias,
                                                  float* __restrict__ out) {
  constexpr int LG = 4, NPB = 64, SPB = SLICE / NPB;
  int t  = threadIdx.x;
  int q  = t & (LG - 1);
  int bi = blockIdx.x;
  int vb = (bi & 7) * SPB + (bi >> 3);
  int i  = vb * NPB + t / LG;
  int gl = (t & 63) & ~(LG - 1);
  float4 acc = agg_core<16, 16>(g, csr, row_start[i], row_end[i], q, gl);
  float di = dinv[i];
  float4 bb = *(const float4*)(bias + q * 4);
  acc.x = fmaxf(fmaf(di, acc.x, bb.x), 0.f) * di;
  acc.y = fmaxf(fmaf(di, acc.y, bb.y), 0.f) * di;
  acc.z = fmaxf(fmaf(di, acc.z, bb.z), 0.f) * di;
  acc.w = fmaxf(fmaf(di, acc.w, bb.w), 0.f) * di;
  *(float4*)(out + (size_t)i * 16 + q * 4) = acc;
}

// ---------------- K3: a2 = dinv·Σg1 ; g2 = dinv ⊙ relu(a2@W2+b2) (16->32) ----

__global__ __launch_bounds__(256) void k_agg_g2(const float* __restrict__ g,
                                                const int* __restrict__ row_start,
                                                const int* __restrict__ row_end,
                                                const int* __restrict__ csr,
                                                const float* __restrict__ dinv,
                                                const float* __restrict__ W2,
                                                const float* __restrict__ b2,
                                                float* __restrict__ out) {
  constexpr int CI = 16, CO = 32, LG = 4, NPB = 64, SPB = SLICE / NPB, RP = 20;
  __shared__ float sW[CI * CO];
  __shared__ float sB[CO];
  __shared__ float rows[NPB * RP];
  __shared__ float sdi[NPB];
  int t = threadIdx.x;
  for (int k = t; k < CI * CO; k += 256) sW[k] = W2[k];
  if (t < CO) sB[t] = b2[t];
  int bi = blockIdx.x;
  int vb = (bi & 7) * SPB + (bi >> 3);
  int nbase = vb * NPB;
  int q = t & (LG - 1), nl = t / LG;
  int i = nbase + nl;
  int gl = (t & 63) & ~(LG - 1);
  float4 acc = agg_core<16, 16>(g, csr, row_start[i], row_end[i], q, gl);
  float di = dinv[i];
  acc.x *= di; acc.y *= di; acc.z *= di; acc.w *= di;
  *(float4*)&rows[nl * RP + q * 4] = acc;
  if (q == 0) sdi[nl] = di;
  __syncthreads();
  int n2 = t >> 2, c = t & 3;                  // 4 threads/node, 8 outs each
  float o[8];
#pragma unroll
  for (int j = 0; j < 8; ++j) o[j] = sB[c * 8 + j];
  const float* row = &rows[n2 * RP];
#pragma unroll
  for (int k = 0; k < CI; ++k) {
    float rv = row[k];
#pragma unroll
    for (int j = 0; j < 8; ++j) o[j] = fmaf(rv, sW[k * CO + c * 8 + j], o[j]);
  }
  float d2 = sdi[n2];
#pragma unroll
  for (int j = 0; j < 8; ++j) o[j] = fmaxf(o[j], 0.f) * d2;
  float* op = out + (size_t)(nbase + n2) * CO + c * 8;
  *(float4*)op       = make_float4(o[0], o[1], o[2], o[3]);
  *(float4*)(op + 4) = make_float4(o[4], o[5], o[6], o[7]);
}

// ---- K4: a3 = dinv·Σg2 ; h3 = relu(a3@W3+b3); g4 = dinv⊙(h3@W4) (32->64->32) --
// W3/W4 staged to LDS before the gather (overlapped), EPI=8.

__global__ __launch_bounds__(256) void k_agg_g34(const float* __restrict__ g,
                                                 const int* __restrict__ row_start,
                                                 const int* __restrict__ row_end,
                                                 const int* __restrict__ csr,
                                                 const float* __restrict__ dinv,
                                                 const float* __restrict__ W3,
                                                 const float* __restrict__ b3,
                                                 const float* __restrict__ W4,
                                                 float* __restrict__ out) {
  constexpr int LG = 8, NPB = 32, SPB = SLICE / NPB, RP = 36, HP = 68;
  __shared__ float sW3[32 * 64];
  __shared__ float sW4[64 * 32];
  __shared__ float sB3[64];
  __shared__ float rows[NPB * RP];
  __shared__ float hrows[NPB * HP];
  __shared__ float sdi[NPB];
  int t = threadIdx.x;
  for (int k = t; k < 2048; k += 256) { sW3[k] = W3[k]; sW4[k] = W4[k]; }
  if (t < 64) sB3[t] = b3[t];
  int bi = blockIdx.x;
  int vb = (bi & 7) * SPB + (bi >> 3);
  int nbase = vb * NPB;
  int q = t & (LG - 1), nl = t / LG;
  int i = nbase + nl;
  int gl = (t & 63) & ~(LG - 1);
  float4 acc = agg_core<32, 8>(g, csr, row_start[i], row_end[i], q, gl);
  float di = dinv[i];
  acc.x *= di; acc.y *= di; acc.z *= di; acc.w *= di;
  *(float4*)&rows[nl * RP + q * 4] = acc;
  if (q == 0) sdi[nl] = di;
  __syncthreads();
  int n2 = t >> 3, c = t & 7;                  // 8 threads/node
  {                                            // stage 1: 8 of 64 h each
    float o[8];
#pragma unroll
    for (int j = 0; j < 8; ++j) o[j] = sB3[c * 8 + j];
    const float* row = &rows[n2 * RP];
#pragma unroll
    for (int k = 0; k < 32; ++k) {
      float rv = row[k];
#pragma unroll
      for (int j = 0; j < 8; ++j) o[j] = fmaf(rv, sW3[k * 64 + c * 8 + j], o[j]);
    }
    float* hp = &hrows[n2 * HP + c * 8];
#pragma unroll
    for (int j = 0; j < 8; ++j) hp[j] = fmaxf(o[j], 0.f);
  }
  __syncthreads();
  {                                            // stage 2: 4 of 32 outs each
    float o[4] = {0.f, 0.f, 0.f, 0.f};
    const float* hp = &hrows[n2 * HP];
#pragma unroll
    for (int k = 0; k < 64; ++k) {
      float hv = hp[k];
#pragma unroll
      for (int j = 0; j < 4; ++j) o[j] = fmaf(hv, sW4[k * 32 + c * 4 + j], o[j]);
    }
    float d2 = sdi[n2];
#pragma unroll
    for (int j = 0; j < 4; ++j) o[j] *= d2;
    *(float4*)(out + (size_t)(nbase + n2) * 32 + c * 4)
        = make_float4(o[0], o[1], o[2], o[3]);
  }
}

// ---- K5: h4 = relu(dinv·Σg4 + b4); g5 = dinv⊙(h4@W5)  (32->16), EPI=8 ----

__global__ __launch_bounds__(256) void k_agg_g5(const float* __restrict__ g,
                                                const int* __restrict__ row_start,
                                                const int* __restrict__ row_end,
                                                const int* __restrict__ csr,
                                                const float* __restrict__ dinv,
                                                const float* __restrict__ b4,
                                                const float* __restrict__ W5,
                                                float* __restrict__ out) {
  constexpr int LG = 8, NPB = 32, SPB = SLICE / NPB, RP = 36;
  __shared__ float sW[32 * 16];
  __shared__ float rows[NPB * RP];
  __shared__ float sdi[NPB];
  int t = threadIdx.x;
  for (int k = t; k < 512; k += 256) sW[k] = W5[k];
  int bi = blockIdx.x;
  int vb = (bi & 7) * SPB + (bi >> 3);
  int nbase = vb * NPB;
  int q = t & (LG - 1), nl = t / LG;
  int i = nbase + nl;
  int gl = (t & 63) & ~(LG - 1);
  float4 acc = agg_core<32, 8>(g, csr, row_start[i], row_end[i], q, gl);
  float di = dinv[i];
  float4 bb = *(const float4*)(b4 + q * 4);
  acc.x = fmaxf(fmaf(di, acc.x, bb.x), 0.f);
  acc.y = fmaxf(fmaf(di, acc.y, bb.y), 0.f);
  acc.z = fmaxf(fmaf(di, acc.z, bb.z), 0.f);
  acc.w = fmaxf(fmaf(di, acc.w, bb.w), 0.f);
  *(float4*)&rows[nl * RP + q * 4] = acc;
  if (q == 0) sdi[nl] = di;
  __syncthreads();
  int n2 = t >> 3, c = t & 7;                  // 8 threads/node, 2 outs each
  float o0 = 0.f, o1 = 0.f;
  const float* row = &rows[n2 * RP];
#pragma unroll
  for (int k = 0; k < 32; ++k) {
    float rv = row[k];
    o0 = fmaf(rv, sW[k * 16 + c * 2],     o0);
    o1 = fmaf(rv, sW[k * 16 + c * 2 + 1], o1);
  }
  float d2 = sdi[n2];
  *(float2*)(out + (size_t)(nbase + n2) * 16 + c * 2) = make_float2(o0 * d2, o1 * d2);
}

// ---- K6: h5 = relu(dinv·Σg5 + b5); out = relu(h5@fW1+fb1)@fW2+fb2 --------

__global__ __launch_bounds__(256) void k_agg_mlp(const float* __restrict__ g,
                                                 const int* __restrict__ row_start,
                                                 const int* __restrict__ row_end,
                                                 const int* __restrict__ csr,
                                                 const float* __restrict__ dinv,
                                                 const float* __restrict__ b5,
                                                 const float* __restrict__ fW1,
                                                 const float* __restrict__ fb1,
                                                 const float* __restrict__ fW2,
                                                 const float* __restrict__ fb2,
                                                 float* __restrict__ out) {
  constexpr int LG = 4, NPB = 64, SPB = SLICE / NPB, RP = 20;
  __shared__ float sW1[256], sW2[144], sB1[16], sB2[9];
  __shared__ float rows[NPB * RP];
  __shared__ float zrows[NPB * RP];
  __shared__ float ost[NPB * 9];
  int t = threadIdx.x;
  sW1[t] = fW1[t];
  if (t < 144) sW2[t] = fW2[t];
  if (t < 16)  sB1[t] = fb1[t];
  if (t < 9)   sB2[t] = fb2[t];
  int bi = blockIdx.x;
  int vb = (bi & 7) * SPB + (bi >> 3);
  int nbase = vb * NPB;
  int q = t & (LG - 1), nl = t / LG;
  int i = nbase + nl;
  int gl = (t & 63) & ~(LG - 1);
  float4 acc = agg_core<16, 16>(g, csr, row_start[i], row_end[i], q, gl);
  float di = dinv[i];
  float4 bb = *(const float4*)(b5 + q * 4);
  acc.x = fmaxf(fmaf(di, acc.x, bb.x), 0.f);
  acc.y = fmaxf(fmaf(di, acc.y, bb.y), 0.f);
  acc.z = fmaxf(fmaf(di, acc.z, bb.z), 0.f);
  acc.w = fmaxf(fmaf(di, acc.w, bb.w), 0.f);
  *(float4*)&rows[nl * RP + q * 4] = acc;
  __syncthreads();
  int n2 = t >> 2, c = t & 3;                  // 4 threads/node
  {                                            // z = relu(h5@fW1+fb1), 4 each
    float o[4];
#pragma unroll
    for (int j = 0; j < 4; ++j) o[j] = sB1[c * 4 + j];
    const float* row = &rows[n2 * RP];
#pragma unroll
    for (int k = 0; k < 16; ++k) {
      float rv = row[k];
#pragma unroll
      for (int j = 0; j < 4; ++j) o[j] = fmaf(rv, sW1[k * 16 + c * 4 + j], o[j]);
    }
    float* zp = &zrows[n2 * RP + c * 4];
#pragma unroll
    for (int j = 0; j < 4; ++j) zp[j] = fmaxf(o[j], 0.f);
  }
  __syncthreads();
  if (c < 3) {                                 // 3 outs each (3x3 = 9)
    float o[3];
#pragma unroll
    for (int j = 0; j < 3; ++j) o[j] = sB2[c * 3 + j];
    const float* zp = &zrows[n2 * RP];
#pragma unroll
    for (int k = 0; k < 16; ++k) {
      float zv = zp[k];
#pragma unroll
      for (int j = 0; j < 3; ++j) o[j] = fmaf(zv, sW2[k * 9 + c * 3 + j], o[j]);
    }
#pragma unroll
    for (int j = 0; j < 3; ++j) ost[n2 * 9 + c * 3 + j] = o[j];
  }
  __syncthreads();
  float* ob = out + (size_t)nbase * 9;
  for (int k = t; k < NPB * 9; k += 256) ob[k] = ost[k];
}

// ---------------- launch ----------------

extern "C" void kernel_launch(void* const* d_in, const int* in_sizes, int n_in,
                              void* d_out, int out_size, void* d_ws, size_t ws_size,
                              hipStream_t stream) {
  const float* x   = (const float*)d_in[0];
  const int*   ei  = (const int*)d_in[1];
  const float* W1  = (const float*)d_in[2];
  const float* b1  = (const float*)d_in[3];
  const float* W2  = (const float*)d_in[4];
  const float* b2  = (const float*)d_in[5];
  const float* W3  = (const float*)d_in[6];
  const float* b3  = (const float*)d_in[7];
  const float* W4  = (const float*)d_in[8];
  const float* b4  = (const float*)d_in[9];
  const float* W5  = (const float*)d_in[10];
  const float* b5  = (const float*)d_in[11];
  const float* fW1 = (const float*)d_in[12];
  const float* fb1 = (const float*)d_in[13];
  const float* fW2 = (const float*)d_in[14];
  const float* fb2 = (const float*)d_in[15];
  float* out = (float*)d_out;

  char* ws = (char*)d_ws;
  size_t off = 0;
  auto alloc = [&](size_t bytes) -> char* {
    char* p = ws + off;
    off += (bytes + 255) & ~(size_t)255;
    return p;
  };
  int*   counts  = (int*)  alloc((size_t)NBLK * NBKT * 4);
  int*   basesT  = (int*)  alloc((size_t)NBKT * NBLK * 4);
  int*   btot    = (int*)  alloc((size_t)NBKT * 4);
  unsigned int* pairs = (unsigned int*)alloc((size_t)NEDGE * 4);
  int*   rs_     = (int*)  alloc((size_t)NN * 4);
  int*   re_     = (int*)  alloc((size_t)NN * 4);
  float* dinv    = (float*)alloc((size_t)NN * 4);
  int*   csr     = (int*)  alloc((size_t)ETOT * 4);
  float* P16a    = (float*)alloc((size_t)NN * 16 * 4);
  float* P16b    = (float*)alloc((size_t)NN * 16 * 4);
  float* P32a    = (float*)alloc((size_t)NN * 32 * 4);
  float* P32b    = (float*)alloc((size_t)NN * 32 * 4);

  k_count<<<NBLK, 256, 0, stream>>>(ei, counts);
  k_scan <<<NBKT, 256, 0, stream>>>(counts, basesT, btot);
  k_scat <<<NBLK, 256, 0, stream>>>(ei, basesT, btot, pairs);
  // k_build + fused K1: csr/dinv/bounds + g0 = dinv⊙(x@W1)
  k_build<<<NBKT, 256, 0, stream>>>(pairs, btot, x, W1, rs_, re_, dinv, csr, P16a);

  // K2: g1 = dinv⊙relu(dinv·Σg0 + b1)
  k_agg_ep16<<<NN / 64, 256, 0, stream>>>(P16a, rs_, re_, csr, dinv, b1, P16b);
  // K3: g2 = dinv⊙relu((dinv·Σg1)@W2 + b2)
  k_agg_g2<<<NN / 64, 256, 0, stream>>>(P16b, rs_, re_, csr, dinv, W2, b2, P32a);
  // K4: g4 = dinv⊙(relu((dinv·Σg2)@W3+b3)@W4)
  k_agg_g34<<<NN / 32, 256, 0, stream>>>(P32a, rs_, re_, csr, dinv, W3, b3, W4, P32b);
  // K5: g5 = dinv⊙(relu(dinv·Σg4 + b4)@W5)
  k_agg_g5<<<NN / 32, 256, 0, stream>>>(P32b, rs_, re_, csr, dinv, b4, W5, P16a);
  // K6: head MLP on h5 = relu(dinv·Σg5 + b5)
  k_agg_mlp<<<NN / 64, 256, 0, stream>>>(P16a, rs_, re_, csr, dinv, b5,
                                         fW1, fb1, fW2, fb2, out);
}

// Round 9
// 450.795 us; speedup vs baseline: 1.0469x; 1.0469x over previous
//
#include <hip/hip_runtime.h>

// Sudoku GNN: 5x GCNConv (shared graph) + 2-layer MLP head.
// CSR via two-level bucket sort (no global atomics). Weight-free CSR
// (dinv factored into producers/consumers). Pull-based aggs fused with
// the following dense stage through LDS row staging.
// Per-kernel gather depth (measured): K4 (30KB LDS, 5 blk/CU) best at
// EPI=8; K5/K2/K3/K6 (light LDS, 8 blk/CU) best at EPI=16.

#define NN    165888            // total nodes = 2048*81
#define NBAT  2048
#define EPER  1620
#define NEDGE (NBAT * EPER)     // 3,317,760
#define ETOT  (NEDGE + NN)      // 3,483,648 (with self loops)
#define NBKT  648               // buckets of 256 nodes (dst>>8)
#define NBLK  512               // edge-pass blocks, 4 batches each
#define SLICE 20736             // NN/8 (XCD swizzle for node-parallel kernels)
#define BCAP  6144              // LDS pairs cache per bucket (mean 5120)

// ---------------- block-wide exclusive scan (256 threads) ----------------

__device__ inline void blk_scan256(int val, int& excl, int& total, int* sw) {
  int lane = threadIdx.x & 63, w = threadIdx.x >> 6;
  int x = val;
#pragma unroll
  for (int off = 1; off < 64; off <<= 1) {
    int y = __shfl_up(x, off);
    if (lane >= off) x += y;
  }
  if (lane == 63) sw[w] = x;
  __syncthreads();
  int woff = 0;
  if (w > 0) woff = sw[0];
  if (w > 1) woff += sw[1];
  if (w > 2) woff += sw[2];
  total = sw[0] + sw[1] + sw[2] + sw[3];
  excl = woff + x - val;
}

// Exclusive prefix of btot[648] into LDS pb[648] (3 elements/thread, 648=3*216).
__device__ inline void pbase_scan(const int* __restrict__ btot, int* pb, int* sw) {
  int t = threadIdx.x;
  int e0 = 0, e1 = 0, e2 = 0, s = 0;
  if (t < 216) {
    e0 = btot[3 * t]; e1 = btot[3 * t + 1]; e2 = btot[3 * t + 2];
    s = e0 + e1 + e2;
  }
  int excl, tot;
  blk_scan256(s, excl, tot, sw);
  if (t < 216) {
    pb[3 * t]     = excl;
    pb[3 * t + 1] = excl + e0;
    pb[3 * t + 2] = excl + e0 + e1;
  }
  __syncthreads();
}

// ---------------- preprocessing ----------------

__global__ __launch_bounds__(256) void k_count(const int* __restrict__ ei,
                                               int* __restrict__ counts) {
  __shared__ int cnt[NBKT];
  int t = threadIdx.x;
  for (int k = t; k < NBKT; k += 256) cnt[k] = 0;
  __syncthreads();
  int b0 = blockIdx.x * 4;
  for (int b = b0; b < b0 + 4; ++b) {
    const int* dstp = ei + (size_t)b * (2 * EPER) + EPER;
    for (int e = t; e < EPER; e += 256) atomicAdd(&cnt[dstp[e] >> 8], 1);
  }
  __syncthreads();
  for (int k = t; k < NBKT; k += 256) counts[blockIdx.x * NBKT + k] = cnt[k];
}

__global__ __launch_bounds__(256) void k_scan(const int* __restrict__ counts,
                                              int* __restrict__ basesT,
                                              int* __restrict__ btot) {
  int bkt = blockIdx.x, t = threadIdx.x;
  int a = counts[(2 * t)     * NBKT + bkt];
  int b = counts[(2 * t + 1) * NBKT + bkt];
  __shared__ int sw[4];
  int excl, tot;
  blk_scan256(a + b, excl, tot, sw);
  basesT[bkt * NBLK + 2 * t]     = excl;
  basesT[bkt * NBLK + 2 * t + 1] = excl + a;
  if (t == 255) btot[bkt] = tot;
}

__global__ __launch_bounds__(256) void k_scat(const int* __restrict__ ei,
                                              const int* __restrict__ basesT,
                                              const int* __restrict__ btot,
                                              unsigned int* __restrict__ pairs) {
  __shared__ int cur[NBKT];
  __shared__ int pb[NBKT];
  __shared__ int sw[4];
  pbase_scan(btot, pb, sw);
  int t = threadIdx.x;
  for (int k = t; k < NBKT; k += 256)
    cur[k] = pb[k] + basesT[k * NBLK + blockIdx.x];
  __syncthreads();
  int b0 = blockIdx.x * 4;
  for (int b = b0; b < b0 + 4; ++b) {
    const int* srcp = ei + (size_t)b * (2 * EPER);
    const int* dstp = srcp + EPER;
    for (int e = t; e < EPER; e += 256) {
      int d = dstp[e];
      unsigned int s = (unsigned int)srcp[e];
      int pos = atomicAdd(&cur[d >> 8], 1);
      pairs[pos] = s | ((unsigned int)(d & 255) << 24);
    }
  }
}

// k_build (+fused K1 gemm): CSR rows for one bucket (pairs cached in LDS,
// single global read), dinv, self loops, then g0 = dinv ⊙ (x @ W1).
__global__ __launch_bounds__(256) void k_build(const unsigned int* __restrict__ pairs,
                                               const int* __restrict__ btot,
                                               const float* __restrict__ x,
                                               const float* __restrict__ W1,
                                               int* __restrict__ row_start,
                                               int* __restrict__ row_end,
                                               float* __restrict__ dinv,
                                               int* __restrict__ csr,
                                               float* __restrict__ g0) {
  __shared__ int pb[NBKT];
  __shared__ int sw[4];
  __shared__ int cnt[256];
  __shared__ unsigned int sp[BCAP];
  __shared__ float sW[160];
  int bkt = blockIdx.x, t = threadIdx.x;
  cnt[t] = 0;
  if (t < 160) sW[t] = W1[t];
  pbase_scan(btot, pb, sw);                     // trailing sync orders cnt/sW too
  int p0 = pb[bkt];
  int n  = btot[bkt];
  // single global pass: cache in LDS + histogram
  for (int k = t; k < n; k += 256) {
    unsigned int pr = pairs[p0 + k];
    if (k < BCAP) sp[k] = pr;
    atomicAdd(&cnt[pr >> 24], 1);
  }
  __syncthreads();
  int indeg = cnt[t];
  int excl, tot;
  blk_scan256(indeg, excl, tot, sw);
  int csrbase = p0 + bkt * 256;                 // + self-loop slots of prior buckets
  int rs   = csrbase + excl + t;
  int node = bkt * 256 + t;
  int d    = indeg + 1;
  float di = rsqrtf((float)d);
  row_start[node] = rs;
  row_end[node]   = rs + d;
  dinv[node] = di;
  csr[rs] = node;                               // self loop
  __syncthreads();
  cnt[t] = rs + 1;                              // reuse as cursors
  __syncthreads();
  for (int k = t; k < n; k += 256) {
    unsigned int pr = (k < BCAP) ? sp[k] : pairs[p0 + k];
    int pos = atomicAdd(&cnt[pr >> 24], 1);
    csr[pos] = (int)(pr & 0x00FFFFFFu);
  }
  // fused K1: g0 = dinv ⊙ (x @ W1)  (10 -> 16)
  float r[10];
#pragma unroll
  for (int k = 0; k < 10; ++k) r[k] = x[(size_t)node * 10 + k];
  float acc[16];
#pragma unroll
  for (int j = 0; j < 16; ++j) acc[j] = 0.0f;
#pragma unroll
  for (int k = 0; k < 10; ++k) {
    float rv = r[k];
#pragma unroll
    for (int j = 0; j < 16; ++j) acc[j] = fmaf(rv, sW[k * 16 + j], acc[j]);
  }
  float* op = g0 + (size_t)node * 16;
#pragma unroll
  for (int j = 0; j < 16; j += 4)
    *(float4*)(op + j) = make_float4(acc[j] * di, acc[j+1] * di,
                                     acc[j+2] * di, acc[j+3] * di);
}

// ------------- branchless agg core: EPI gathers in flight -------------
// Clamped slots all read row re-1; sum unweighted, subtract dups*v_last.

template <int C, int EPI>
__device__ inline float4 agg_core(const float* __restrict__ g,
                                  const int* __restrict__ csr,
                                  int rs, int re, int q, int gl) {
  constexpr int LG = C / 4;
  float4 acc = make_float4(0.f, 0.f, 0.f, 0.f);
  const float* gq = g + (size_t)q * 4;
  int iters = 0;
  for (int p = rs; p < re; p += EPI) {
    ++iters;
    int m[EPI / LG];
#pragma unroll
    for (int u = 0; u < EPI / LG; ++u) {
      int idx = p + u * LG + q;
      m[u] = csr[idx < re ? idx : re - 1];
    }
    float4 v[EPI];
#pragma unroll
    for (int j = 0; j < EPI; ++j) {
      int s = __shfl(m[j / LG], gl + (j % LG));
      v[j] = *(const float4*)(gq + (size_t)s * C);
    }
#pragma unroll
    for (int j = 0; j < EPI; ++j) {
      acc.x += v[j].x; acc.y += v[j].y; acc.z += v[j].z; acc.w += v[j].w;
    }
  }
  float dups = (float)(iters * EPI - (re - rs));
  int slast = csr[re - 1];
  float4 vl = *(const float4*)(gq + (size_t)slast * C);
  acc.x = fmaf(-dups, vl.x, acc.x);
  acc.y = fmaf(-dups, vl.y, acc.y);
  acc.z = fmaf(-dups, vl.z, acc.z);
  acc.w = fmaf(-dups, vl.w, acc.w);
  return acc;
}

// ---------------- K2: g1 = dinv ⊙ relu(dinv·Σg0 + b1)  (C=16) ----------------

__global__ __launch_bounds__(256) void k_agg_ep16(const float* __restrict__ g,
                                                  const int* __restrict__ row_start,
                                                  const int* __restrict__ row_end,
                                                  const int* __restrict__ csr,
                                                  const float* __restrict__ dinv,
                                                  const float* __restrict__ bias,
                                                  float* __restrict__ out) {
  constexpr int LG = 4, NPB = 64, SPB = SLICE / NPB;
  int t  = threadIdx.x;
  int q  = t & (LG - 1);
  int bi = blockIdx.x;
  int vb = (bi & 7) * SPB + (bi >> 3);
  int i  = vb * NPB + t / LG;
  int gl = (t & 63) & ~(LG - 1);
  float4 acc = agg_core<16, 16>(g, csr, row_start[i], row_end[i], q, gl);
  float di = dinv[i];
  float4 bb = *(const float4*)(bias + q * 4);
  acc.x = fmaxf(fmaf(di, acc.x, bb.x), 0.f) * di;
  acc.y = fmaxf(fmaf(di, acc.y, bb.y), 0.f) * di;
  acc.z = fmaxf(fmaf(di, acc.z, bb.z), 0.f) * di;
  acc.w = fmaxf(fmaf(di, acc.w, bb.w), 0.f) * di;
  *(float4*)(out + (size_t)i * 16 + q * 4) = acc;
}

// ---------------- K3: a2 = dinv·Σg1 ; g2 = dinv ⊙ relu(a2@W2+b2) (16->32) ----

__global__ __launch_bounds__(256) void k_agg_g2(const float* __restrict__ g,
                                                const int* __restrict__ row_start,
                                                const int* __restrict__ row_end,
                                                const int* __restrict__ csr,
                                                const float* __restrict__ dinv,
                                                const float* __restrict__ W2,
                                                const float* __restrict__ b2,
                                                float* __restrict__ out) {
  constexpr int CI = 16, CO = 32, LG = 4, NPB = 64, SPB = SLICE / NPB, RP = 20;
  __shared__ float sW[CI * CO];
  __shared__ float sB[CO];
  __shared__ float rows[NPB * RP];
  __shared__ float sdi[NPB];
  int t = threadIdx.x;
  for (int k = t; k < CI * CO; k += 256) sW[k] = W2[k];
  if (t < CO) sB[t] = b2[t];
  int bi = blockIdx.x;
  int vb = (bi & 7) * SPB + (bi >> 3);
  int nbase = vb * NPB;
  int q = t & (LG - 1), nl = t / LG;
  int i = nbase + nl;
  int gl = (t & 63) & ~(LG - 1);
  float4 acc = agg_core<16, 16>(g, csr, row_start[i], row_end[i], q, gl);
  float di = dinv[i];
  acc.x *= di; acc.y *= di; acc.z *= di; acc.w *= di;
  *(float4*)&rows[nl * RP + q * 4] = acc;
  if (q == 0) sdi[nl] = di;
  __syncthreads();
  int n2 = t >> 2, c = t & 3;                  // 4 threads/node, 8 outs each
  float o[8];
#pragma unroll
  for (int j = 0; j < 8; ++j) o[j] = sB[c * 8 + j];
  const float* row = &rows[n2 * RP];
#pragma unroll
  for (int k = 0; k < CI; ++k) {
    float rv = row[k];
#pragma unroll
    for (int j = 0; j < 8; ++j) o[j] = fmaf(rv, sW[k * CO + c * 8 + j], o[j]);
  }
  float d2 = sdi[n2];
#pragma unroll
  for (int j = 0; j < 8; ++j) o[j] = fmaxf(o[j], 0.f) * d2;
  float* op = out + (size_t)(nbase + n2) * CO + c * 8;
  *(float4*)op       = make_float4(o[0], o[1], o[2], o[3]);
  *(float4*)(op + 4) = make_float4(o[4], o[5], o[6], o[7]);
}

// ---- K4: a3 = dinv·Σg2 ; h3 = relu(a3@W3+b3); g4 = dinv⊙(h3@W4) (32->64->32) --
// W3/W4 staged to LDS before the gather (overlapped), EPI=8.

__global__ __launch_bounds__(256) void k_agg_g34(const float* __restrict__ g,
                                                 const int* __restrict__ row_start,
                                                 const int* __restrict__ row_end,
                                                 const int* __restrict__ csr,
                                                 const float* __restrict__ dinv,
                                                 const float* __restrict__ W3,
                                                 const float* __restrict__ b3,
                                                 const float* __restrict__ W4,
                                                 float* __restrict__ out) {
  constexpr int LG = 8, NPB = 32, SPB = SLICE / NPB, RP = 36, HP = 68;
  __shared__ float sW3[32 * 64];
  __shared__ float sW4[64 * 32];
  __shared__ float sB3[64];
  __shared__ float rows[NPB * RP];
  __shared__ float hrows[NPB * HP];
  __shared__ float sdi[NPB];
  int t = threadIdx.x;
  for (int k = t; k < 2048; k += 256) { sW3[k] = W3[k]; sW4[k] = W4[k]; }
  if (t < 64) sB3[t] = b3[t];
  int bi = blockIdx.x;
  int vb = (bi & 7) * SPB + (bi >> 3);
  int nbase = vb * NPB;
  int q = t & (LG - 1), nl = t / LG;
  int i = nbase + nl;
  int gl = (t & 63) & ~(LG - 1);
  float4 acc = agg_core<32, 8>(g, csr, row_start[i], row_end[i], q, gl);
  float di = dinv[i];
  acc.x *= di; acc.y *= di; acc.z *= di; acc.w *= di;
  *(float4*)&rows[nl * RP + q * 4] = acc;
  if (q == 0) sdi[nl] = di;
  __syncthreads();
  int n2 = t >> 3, c = t & 7;                  // 8 threads/node
  {                                            // stage 1: 8 of 64 h each
    float o[8];
#pragma unroll
    for (int j = 0; j < 8; ++j) o[j] = sB3[c * 8 + j];
    const float* row = &rows[n2 * RP];
#pragma unroll
    for (int k = 0; k < 32; ++k) {
      float rv = row[k];
#pragma unroll
      for (int j = 0; j < 8; ++j) o[j] = fmaf(rv, sW3[k * 64 + c * 8 + j], o[j]);
    }
    float* hp = &hrows[n2 * HP + c * 8];
#pragma unroll
    for (int j = 0; j < 8; ++j) hp[j] = fmaxf(o[j], 0.f);
  }
  __syncthreads();
  {                                            // stage 2: 4 of 32 outs each
    float o[4] = {0.f, 0.f, 0.f, 0.f};
    const float* hp = &hrows[n2 * HP];
#pragma unroll
    for (int k = 0; k < 64; ++k) {
      float hv = hp[k];
#pragma unroll
      for (int j = 0; j < 4; ++j) o[j] = fmaf(hv, sW4[k * 32 + c * 4 + j], o[j]);
    }
    float d2 = sdi[n2];
#pragma unroll
    for (int j = 0; j < 4; ++j) o[j] *= d2;
    *(float4*)(out + (size_t)(nbase + n2) * 32 + c * 4)
        = make_float4(o[0], o[1], o[2], o[3]);
  }
}

// ---- K5: h4 = relu(dinv·Σg4 + b4); g5 = dinv⊙(h4@W5)  (32->16), EPI=16 ----
// Light LDS (~7KB) -> high occupancy -> wider gather burst wins (R7 best).

__global__ __launch_bounds__(256) void k_agg_g5(const float* __restrict__ g,
                                                const int* __restrict__ row_start,
                                                const int* __restrict__ row_end,
                                                const int* __restrict__ csr,
                                                const float* __restrict__ dinv,
                                                const float* __restrict__ b4,
                                                const float* __restrict__ W5,
                                                float* __restrict__ out) {
  constexpr int LG = 8, NPB = 32, SPB = SLICE / NPB, RP = 36;
  __shared__ float sW[32 * 16];
  __shared__ float rows[NPB * RP];
  __shared__ float sdi[NPB];
  int t = threadIdx.x;
  for (int k = t; k < 512; k += 256) sW[k] = W5[k];
  int bi = blockIdx.x;
  int vb = (bi & 7) * SPB + (bi >> 3);
  int nbase = vb * NPB;
  int q = t & (LG - 1), nl = t / LG;
  int i = nbase + nl;
  int gl = (t & 63) & ~(LG - 1);
  float4 acc = agg_core<32, 16>(g, csr, row_start[i], row_end[i], q, gl);
  float di = dinv[i];
  float4 bb = *(const float4*)(b4 + q * 4);
  acc.x = fmaxf(fmaf(di, acc.x, bb.x), 0.f);
  acc.y = fmaxf(fmaf(di, acc.y, bb.y), 0.f);
  acc.z = fmaxf(fmaf(di, acc.z, bb.z), 0.f);
  acc.w = fmaxf(fmaf(di, acc.w, bb.w), 0.f);
  *(float4*)&rows[nl * RP + q * 4] = acc;
  if (q == 0) sdi[nl] = di;
  __syncthreads();
  int n2 = t >> 3, c = t & 7;                  // 8 threads/node, 2 outs each
  float o0 = 0.f, o1 = 0.f;
  const float* row = &rows[n2 * RP];
#pragma unroll
  for (int k = 0; k < 32; ++k) {
    float rv = row[k];
    o0 = fmaf(rv, sW[k * 16 + c * 2],     o0);
    o1 = fmaf(rv, sW[k * 16 + c * 2 + 1], o1);
  }
  float d2 = sdi[n2];
  *(float2*)(out + (size_t)(nbase + n2) * 16 + c * 2) = make_float2(o0 * d2, o1 * d2);
}

// ---- K6: h5 = relu(dinv·Σg5 + b5); out = relu(h5@fW1+fb1)@fW2+fb2 --------

__global__ __launch_bounds__(256) void k_agg_mlp(const float* __restrict__ g,
                                                 const int* __restrict__ row_start,
                                                 const int* __restrict__ row_end,
                                                 const int* __restrict__ csr,
                                                 const float* __restrict__ dinv,
                                                 const float* __restrict__ b5,
                                                 const float* __restrict__ fW1,
                                                 const float* __restrict__ fb1,
                                                 const float* __restrict__ fW2,
                                                 const float* __restrict__ fb2,
                                                 float* __restrict__ out) {
  constexpr int LG = 4, NPB = 64, SPB = SLICE / NPB, RP = 20;
  __shared__ float sW1[256], sW2[144], sB1[16], sB2[9];
  __shared__ float rows[NPB * RP];
  __shared__ float zrows[NPB * RP];
  __shared__ float ost[NPB * 9];
  int t = threadIdx.x;
  sW1[t] = fW1[t];
  if (t < 144) sW2[t] = fW2[t];
  if (t < 16)  sB1[t] = fb1[t];
  if (t < 9)   sB2[t] = fb2[t];
  int bi = blockIdx.x;
  int vb = (bi & 7) * SPB + (bi >> 3);
  int nbase = vb * NPB;
  int q = t & (LG - 1), nl = t / LG;
  int i = nbase + nl;
  int gl = (t & 63) & ~(LG - 1);
  float4 acc = agg_core<16, 16>(g, csr, row_start[i], row_end[i], q, gl);
  float di = dinv[i];
  float4 bb = *(const float4*)(b5 + q * 4);
  acc.x = fmaxf(fmaf(di, acc.x, bb.x), 0.f);
  acc.y = fmaxf(fmaf(di, acc.y, bb.y), 0.f);
  acc.z = fmaxf(fmaf(di, acc.z, bb.z), 0.f);
  acc.w = fmaxf(fmaf(di, acc.w, bb.w), 0.f);
  *(float4*)&rows[nl * RP + q * 4] = acc;
  __syncthreads();
  int n2 = t >> 2, c = t & 3;                  // 4 threads/node
  {                                            // z = relu(h5@fW1+fb1), 4 each
    float o[4];
#pragma unroll
    for (int j = 0; j < 4; ++j) o[j] = sB1[c * 4 + j];
    const float* row = &rows[n2 * RP];
#pragma unroll
    for (int k = 0; k < 16; ++k) {
      float rv = row[k];
#pragma unroll
      for (int j = 0; j < 4; ++j) o[j] = fmaf(rv, sW1[k * 16 + c * 4 + j], o[j]);
    }
    float* zp = &zrows[n2 * RP + c * 4];
#pragma unroll
    for (int j = 0; j < 4; ++j) zp[j] = fmaxf(o[j], 0.f);
  }
  __syncthreads();
  if (c < 3) {                                 // 3 outs each (3x3 = 9)
    float o[3];
#pragma unroll
    for (int j = 0; j < 3; ++j) o[j] = sB2[c * 3 + j];
    const float* zp = &zrows[n2 * RP];
#pragma unroll
    for (int k = 0; k < 16; ++k) {
      float zv = zp[k];
#pragma unroll
      for (int j = 0; j < 3; ++j) o[j] = fmaf(zv, sW2[k * 9 + c * 3 + j], o[j]);
    }
#pragma unroll
    for (int j = 0; j < 3; ++j) ost[n2 * 9 + c * 3 + j] = o[j];
  }
  __syncthreads();
  float* ob = out + (size_t)nbase * 9;
  for (int k = t; k < NPB * 9; k += 256) ob[k] = ost[k];
}

// ---------------- launch ----------------

extern "C" void kernel_launch(void* const* d_in, const int* in_sizes, int n_in,
                              void* d_out, int out_size, void* d_ws, size_t ws_size,
                              hipStream_t stream) {
  const float* x   = (const float*)d_in[0];
  const int*   ei  = (const int*)d_in[1];
  const float* W1  = (const float*)d_in[2];
  const float* b1  = (const float*)d_in[3];
  const float* W2  = (const float*)d_in[4];
  const float* b2  = (const float*)d_in[5];
  const float* W3  = (const float*)d_in[6];
  const float* b3  = (const float*)d_in[7];
  const float* W4  = (const float*)d_in[8];
  const float* b4  = (const float*)d_in[9];
  const float* W5  = (const float*)d_in[10];
  const float* b5  = (const float*)d_in[11];
  const float* fW1 = (const float*)d_in[12];
  const float* fb1 = (const float*)d_in[13];
  const float* fW2 = (const float*)d_in[14];
  const float* fb2 = (const float*)d_in[15];
  float* out = (float*)d_out;

  char* ws = (char*)d_ws;
  size_t off = 0;
  auto alloc = [&](size_t bytes) -> char* {
    char* p = ws + off;
    off += (bytes + 255) & ~(size_t)255;
    return p;
  };
  int*   counts  = (int*)  alloc((size_t)NBLK * NBKT * 4);
  int*   basesT  = (int*)  alloc((size_t)NBKT * NBLK * 4);
  int*   btot    = (int*)  alloc((size_t)NBKT * 4);
  unsigned int* pairs = (unsigned int*)alloc((size_t)NEDGE * 4);
  int*   rs_     = (int*)  alloc((size_t)NN * 4);
  int*   re_     = (int*)  alloc((size_t)NN * 4);
  float* dinv    = (float*)alloc((size_t)NN * 4);
  int*   csr     = (int*)  alloc((size_t)ETOT * 4);
  float* P16a    = (float*)alloc((size_t)NN * 16 * 4);
  float* P16b    = (float*)alloc((size_t)NN * 16 * 4);
  float* P32a    = (float*)alloc((size_t)NN * 32 * 4);
  float* P32b    = (float*)alloc((size_t)NN * 32 * 4);

  k_count<<<NBLK, 256, 0, stream>>>(ei, counts);
  k_scan <<<NBKT, 256, 0, stream>>>(counts, basesT, btot);
  k_scat <<<NBLK, 256, 0, stream>>>(ei, basesT, btot, pairs);
  // k_build + fused K1: csr/dinv/bounds + g0 = dinv⊙(x@W1)
  k_build<<<NBKT, 256, 0, stream>>>(pairs, btot, x, W1, rs_, re_, dinv, csr, P16a);

  // K2: g1 = dinv⊙relu(dinv·Σg0 + b1)
  k_agg_ep16<<<NN / 64, 256, 0, stream>>>(P16a, rs_, re_, csr, dinv, b1, P16b);
  // K3: g2 = dinv⊙relu((dinv·Σg1)@W2 + b2)
  k_agg_g2<<<NN / 64, 256, 0, stream>>>(P16b, rs_, re_, csr, dinv, W2, b2, P32a);
  // K4: g4 = dinv⊙(relu((dinv·Σg2)@W3+b3)@W4)
  k_agg_g34<<<NN / 32, 256, 0, stream>>>(P32a, rs_, re_, csr, dinv, W3, b3, W4, P32b);
  // K5: g5 = dinv⊙(relu(dinv·Σg4 + b4)@W5)
  k_agg_g5<<<NN / 32, 256, 0, stream>>>(P32b, rs_, re_, csr, dinv, b4, W5, P16a);
  // K6: head MLP on h5 = relu(dinv·Σg5 + b5)
  k_agg_mlp<<<NN / 64, 256, 0, stream>>>(P16a, rs_, re_, csr, dinv, b5,
                                         fW1, fb1, fW2, fb2, out);
}